// Round 11
// baseline (233.783 us; speedup 1.0000x reference)
//
#include <hip/hip_runtime.h>
#include <hip/hip_bf16.h>

using bf16 = __hip_bfloat16;
typedef __attribute__((ext_vector_type(8))) short shortx8;  // 8 bf16 = 4 VGPRs (MFMA A/B frag)
typedef __attribute__((ext_vector_type(4))) float f32x4;    // MFMA C/D frag

#define SEQ 8192
#define DM 1024
#define NH 16
#define CHUNK 64
#define NC (SEQ / CHUNK)   // 128
#define NT (DM / 64)       // 16 K-tiles of BK=64

// async global->LDS, 16B per lane; LDS dest is wave-uniform base + lane*16
__device__ __forceinline__ void load_lds16(const bf16* g, bf16* l) {
    __builtin_amdgcn_global_load_lds(
        (const __attribute__((address_space(1))) void*)g,
        (__attribute__((address_space(3))) void*)l, 16, 0, 0);
}

// LDS byte offset (AS(3) pointers are 32-bit on AMDGPU)
__device__ __forceinline__ unsigned ldsoff(const bf16* p) {
    return (unsigned)(unsigned long long)(__attribute__((address_space(3))) const void*)p;
}

// inline-asm ds_read_b128: INVISIBLE to SIInsertWaitcnts, so the compiler
// cannot insert conservative vmcnt(0) drains against outstanding
// global_load_lds (R4-verified: 113us/5.6% MfmaUtil -> 50us/12.4%).
// Consumers fenced with s_waitcnt lgkmcnt(0) + sched_barrier(0) (rule #18).
__device__ __forceinline__ shortx8 dsr128(unsigned a) {
    shortx8 r;
    asm volatile("ds_read_b128 %0, %1" : "=v"(r) : "v"(a));
    return r;
}

__device__ __forceinline__ float bf2f(short s) {
    union { unsigned u; float f; } x;
    x.u = ((unsigned)(unsigned short)s) << 16;
    return x.f;
}

// ---------------------------------------------------------------------------
// One-shot fp32 -> bf16 conversion for xs + 4 weight matrices (unchanged).
// ---------------------------------------------------------------------------
__global__ __launch_bounds__(256) void convert_all(const float* __restrict__ xs,
                                                   const float* __restrict__ wk,
                                                   const float* __restrict__ wv,
                                                   const float* __restrict__ w1,
                                                   const float* __restrict__ w2,
                                                   bf16* __restrict__ xsb,
                                                   bf16* __restrict__ wall) {
    const int b = blockIdx.x;
    const float* in;
    bf16* out;
    int blk;
    if (b < 8192) {
        in = xs; out = xsb; blk = b;
    } else {
        const int seg = (b - 8192) >> 10;      // 0..3, uniform
        blk = (b - 8192) & 1023;
        out = wall + (size_t)seg * DM * DM;
        if (seg == 0)      in = wk;
        else if (seg == 1) in = wv;
        else if (seg == 2) in = w1;
        else               in = w2;
    }
    size_t i = ((size_t)blk * 256 + threadIdx.x) * 4;
    float4 f = *(const float4*)(in + i);
    out[i + 0] = __float2bfloat16(f.x);
    out[i + 1] = __float2bfloat16(f.y);
    out[i + 2] = __float2bfloat16(f.z);
    out[i + 3] = __float2bfloat16(f.w);
}

// ---------------------------------------------------------------------------
// KV projection GEMM — EXACT R9 non-template kernel (R10's re-templating is
// the prime suspect for the 27us regression, rule #19: co-compiled template
// instantiations perturb codegen; R9's composition [non-template KV +
// templated MLP pair] measured KV fine). 256x256, N=2048, 256 blocks,
// R6 2-barrier schedule, asm ds_reads, counted vmcnt, O1 XCD swizzle.
// Fences: F1 = BAR after phase A (B reads done before stageB overwrite);
// F2 = gate vmcnt(4) retiring through A(t+1) + BAR (tile t+1 landed).
// ---------------------------------------------------------------------------
__global__ __launch_bounds__(512, 2) void gemm256(const bf16* __restrict__ A,
                                                  const bf16* __restrict__ B,
                                                  void* __restrict__ Cv,
                                                  float* __restrict__ kappa,
                                                  int N) {
    __shared__ __align__(16) bf16 As[2][256][64];   // 64KB
    __shared__ __align__(16) bf16 Bs[2][256][64];   // 64KB

    const int tid = threadIdx.x;
    const int nwg = gridDim.x * gridDim.y;
    const int bid = blockIdx.x + blockIdx.y * gridDim.x;
    const int cpx = nwg >> 3;                       // nwg % 8 == 0
    const int swz = (bid & 7) * cpx + (bid >> 3);   // bijective XCD chunking
    const int ry  = swz % gridDim.y;                // O1 orientation
    const int rx  = swz / gridDim.y;
    const int bm  = ry * 256;
    const int bn  = rx * 256;

    const int wave = tid >> 6;
    const int lane = tid & 63;
    const int wr   = wave >> 2;        // 0..1
    const int wc   = wave & 3;         // 0..3
    const int quad = lane >> 4;
    const int m16  = lane & 15;
    const int r7   = m16 & 7;
    const int wr128 = wr * 128;
    const int wc64  = wc * 64;
    const int kp0 = ((quad ^ r7) * 8);
    const int kp1 = (((4 + quad) ^ r7) * 8);

    auto stageA = [&](int half, int kt) {
        #pragma unroll
        for (int it = 0; it < 2; ++it) {
            int s = it * 512 + tid;          // 0..1023: (row = s>>3, pos = s&7)
            int row = s >> 3, pos = s & 7;
            int g = pos ^ (row & 7);
            load_lds16(A + (size_t)(bm + half * 128 + row) * DM + kt * 64 + g * 8,
                       &As[kt & 1][half * 128 + row][pos * 8]);
        }
    };
    auto stageB = [&](int half, int kt) {
        #pragma unroll
        for (int it = 0; it < 2; ++it) {
            int s = it * 512 + tid;
            int row = s >> 3, pos = s & 7;
            int g = pos ^ (row & 7);
            load_lds16(B + (size_t)(bn + half * 128 + row) * DM + kt * 64 + g * 8,
                       &Bs[kt & 1][half * 128 + row][pos * 8]);
        }
    };

    f32x4 acc[8][4];
    #pragma unroll
    for (int i = 0; i < 8; ++i)
        #pragma unroll
        for (int j = 0; j < 4; ++j)
            #pragma unroll
            for (int r = 0; r < 4; ++r) acc[i][j][r] = 0.f;

    // prologue: tile0 fully + B(1); tile0 landed via vmcnt(4)
    stageA(0, 0); stageA(1, 0); stageB(0, 0); stageB(1, 0);
    stageB(0, 1); stageB(1, 1);
    asm volatile("s_waitcnt vmcnt(4)");
    __builtin_amdgcn_s_barrier();

    shortx8 af[4][2], blo[2][2], bhi[2][2];

    #pragma unroll 1
    for (int t = 0; t < NT; ++t) {
        const int sl = t & 1;
        // ===== phase A: stage A(t+1), read A-lo + all B, MFMA q0+q1 =====
        if (t + 1 < NT) { stageA(0, t + 1); stageA(1, t + 1); }
        #pragma unroll
        for (int i = 0; i < 4; ++i) {
            af[i][0] = dsr128(ldsoff(&As[sl][wr128 + i * 16 + m16][kp0]));
            af[i][1] = dsr128(ldsoff(&As[sl][wr128 + i * 16 + m16][kp1]));
        }
        #pragma unroll
        for (int j = 0; j < 2; ++j) {
            blo[j][0] = dsr128(ldsoff(&Bs[sl][wc64 + j * 16 + m16][kp0]));
            blo[j][1] = dsr128(ldsoff(&Bs[sl][wc64 + j * 16 + m16][kp1]));
            bhi[j][0] = dsr128(ldsoff(&Bs[sl][wc64 + (j + 2) * 16 + m16][kp0]));
            bhi[j][1] = dsr128(ldsoff(&Bs[sl][wc64 + (j + 2) * 16 + m16][kp1]));
        }
        asm volatile("s_waitcnt lgkmcnt(0)");
        __builtin_amdgcn_sched_barrier(0);
        __builtin_amdgcn_s_setprio(1);
        #pragma unroll
        for (int i = 0; i < 4; ++i)
            #pragma unroll
            for (int j = 0; j < 2; ++j) {
                acc[i][j] = __builtin_amdgcn_mfma_f32_16x16x32_bf16(af[i][0], blo[j][0], acc[i][j], 0, 0, 0);
                acc[i][j] = __builtin_amdgcn_mfma_f32_16x16x32_bf16(af[i][1], blo[j][1], acc[i][j], 0, 0, 0);
                acc[i][j + 2] = __builtin_amdgcn_mfma_f32_16x16x32_bf16(af[i][0], bhi[j][0], acc[i][j + 2], 0, 0, 0);
                acc[i][j + 2] = __builtin_amdgcn_mfma_f32_16x16x32_bf16(af[i][1], bhi[j][1], acc[i][j + 2], 0, 0, 0);
            }
        __builtin_amdgcn_s_setprio(0);
        __builtin_amdgcn_s_barrier();   // F1: all B reads of tile t complete

        // ===== phase B: stage B(t+2), read A-hi, MFMA q2+q3, gate =====
        if (t + 2 < NT) { stageB(0, t + 2); stageB(1, t + 2); }
        #pragma unroll
        for (int i = 0; i < 4; ++i) {
            af[i][0] = dsr128(ldsoff(&As[sl][wr128 + 64 + i * 16 + m16][kp0]));
            af[i][1] = dsr128(ldsoff(&As[sl][wr128 + 64 + i * 16 + m16][kp1]));
        }
        asm volatile("s_waitcnt lgkmcnt(0)");
        __builtin_amdgcn_sched_barrier(0);
        __builtin_amdgcn_s_setprio(1);
        #pragma unroll
        for (int i = 0; i < 4; ++i)
            #pragma unroll
            for (int j = 0; j < 2; ++j) {
                acc[4 + i][j] = __builtin_amdgcn_mfma_f32_16x16x32_bf16(af[i][0], blo[j][0], acc[4 + i][j], 0, 0, 0);
                acc[4 + i][j] = __builtin_amdgcn_mfma_f32_16x16x32_bf16(af[i][1], blo[j][1], acc[4 + i][j], 0, 0, 0);
                acc[4 + i][j + 2] = __builtin_amdgcn_mfma_f32_16x16x32_bf16(af[i][0], bhi[j][0], acc[4 + i][j + 2], 0, 0, 0);
                acc[4 + i][j + 2] = __builtin_amdgcn_mfma_f32_16x16x32_bf16(af[i][1], bhi[j][1], acc[4 + i][j + 2], 0, 0, 0);
            }
        __builtin_amdgcn_s_setprio(0);
        if (t + 2 < NT) {
            asm volatile("s_waitcnt vmcnt(4)");   // retire through A(t+1)
        } else {
            asm volatile("s_waitcnt vmcnt(0)");
        }
        __builtin_amdgcn_s_barrier();   // F2: tile t+1 landed for all waves
    }

    // epilogue: C/D frag layout col = lane&15, row = quad*4 + reg
    const int gcol0 = bn + wc64;
    if (gcol0 < DM) {
        // K side: kappa[h][t] = sum_d act(K[t][h*64+d]); wave = one head
        const int h = gcol0 >> 6;
        #pragma unroll
        for (int i = 0; i < 8; ++i) {
            #pragma unroll
            for (int r = 0; r < 4; ++r) {
                float s = 0.f;
                #pragma unroll
                for (int j = 0; j < 4; ++j) {
                    float v = acc[i][j][r];
                    s += v > 0.f ? v + 1.f : __expf(v);
                }
                s += __shfl_xor(s, 1);
                s += __shfl_xor(s, 2);
                s += __shfl_xor(s, 4);
                s += __shfl_xor(s, 8);
                if (m16 == 0)
                    kappa[(size_t)h * SEQ + bm + wr128 + i * 16 + quad * 4 + r] = s;
            }
        }
    } else {
        // V side: bf16 store into vb
        bf16* vb = (bf16*)Cv;
        #pragma unroll
        for (int i = 0; i < 8; ++i) {
            int row0 = bm + wr128 + i * 16 + quad * 4;
            #pragma unroll
            for (int j = 0; j < 4; ++j) {
                int col = gcol0 - DM + j * 16 + m16;
                #pragma unroll
                for (int r = 0; r < 4; ++r)
                    vb[(size_t)(row0 + r) * DM + col] = __float2bfloat16(acc[i][j][r]);
            }
        }
    }
}

// ---------------------------------------------------------------------------
// MLP GEMM, 256x256-tile structure (R10 measured 49.0us/dispatch vs the
// 128x256 gemm_mlp's locked 64.9us). Separate template pair — matches R9's
// TU composition (non-template KV + one templated MLP pair) to avoid the
// rule-#19 co-compilation suspect from R10's all-in-one template.
// Grid (DM/256, SEQ/256) = (4,32) = 128 blocks (half chip; per-block time
// is occupancy-independent per R4/R10 evidence).
// MODE 2: +bias, tanh-gelu -> bf16.  MODE 3: +bias -> fp32 (final output).
// C row stride = DM (=N for both MLP GEMMs).
// ---------------------------------------------------------------------------
template <int MODE>
__global__ __launch_bounds__(512, 2) void gemm_mlp256(const bf16* __restrict__ A,
                                                      const bf16* __restrict__ B,
                                                      void* __restrict__ Cv,
                                                      const float* __restrict__ bias) {
    __shared__ __align__(16) bf16 As[2][256][64];   // 64KB
    __shared__ __align__(16) bf16 Bs[2][256][64];   // 64KB

    const int tid = threadIdx.x;
    const int nwg = gridDim.x * gridDim.y;
    const int bid = blockIdx.x + blockIdx.y * gridDim.x;
    const int cpx = nwg >> 3;                       // 128/8 = 16
    const int swz = (bid & 7) * cpx + (bid >> 3);   // bijective XCD chunking
    const int ry  = swz % gridDim.y;                // O1 orientation
    const int rx  = swz / gridDim.y;
    const int bm  = ry * 256;
    const int bn  = rx * 256;

    const int wave = tid >> 6;
    const int lane = tid & 63;
    const int wr   = wave >> 2;
    const int wc   = wave & 3;
    const int quad = lane >> 4;
    const int m16  = lane & 15;
    const int r7   = m16 & 7;
    const int wr128 = wr * 128;
    const int wc64  = wc * 64;
    const int kp0 = ((quad ^ r7) * 8);
    const int kp1 = (((4 + quad) ^ r7) * 8);

    auto stageA = [&](int half, int kt) {
        #pragma unroll
        for (int it = 0; it < 2; ++it) {
            int s = it * 512 + tid;
            int row = s >> 3, pos = s & 7;
            int g = pos ^ (row & 7);
            load_lds16(A + (size_t)(bm + half * 128 + row) * DM + kt * 64 + g * 8,
                       &As[kt & 1][half * 128 + row][pos * 8]);
        }
    };
    auto stageB = [&](int half, int kt) {
        #pragma unroll
        for (int it = 0; it < 2; ++it) {
            int s = it * 512 + tid;
            int row = s >> 3, pos = s & 7;
            int g = pos ^ (row & 7);
            load_lds16(B + (size_t)(bn + half * 128 + row) * DM + kt * 64 + g * 8,
                       &Bs[kt & 1][half * 128 + row][pos * 8]);
        }
    };

    f32x4 acc[8][4];
    #pragma unroll
    for (int i = 0; i < 8; ++i)
        #pragma unroll
        for (int j = 0; j < 4; ++j)
            #pragma unroll
            for (int r = 0; r < 4; ++r) acc[i][j][r] = 0.f;

    stageA(0, 0); stageA(1, 0); stageB(0, 0); stageB(1, 0);
    stageB(0, 1); stageB(1, 1);
    asm volatile("s_waitcnt vmcnt(4)");
    __builtin_amdgcn_s_barrier();

    shortx8 af[4][2], blo[2][2], bhi[2][2];

    #pragma unroll 1
    for (int t = 0; t < NT; ++t) {
        const int sl = t & 1;
        // ===== phase A =====
        if (t + 1 < NT) { stageA(0, t + 1); stageA(1, t + 1); }
        #pragma unroll
        for (int i = 0; i < 4; ++i) {
            af[i][0] = dsr128(ldsoff(&As[sl][wr128 + i * 16 + m16][kp0]));
            af[i][1] = dsr128(ldsoff(&As[sl][wr128 + i * 16 + m16][kp1]));
        }
        #pragma unroll
        for (int j = 0; j < 2; ++j) {
            blo[j][0] = dsr128(ldsoff(&Bs[sl][wc64 + j * 16 + m16][kp0]));
            blo[j][1] = dsr128(ldsoff(&Bs[sl][wc64 + j * 16 + m16][kp1]));
            bhi[j][0] = dsr128(ldsoff(&Bs[sl][wc64 + (j + 2) * 16 + m16][kp0]));
            bhi[j][1] = dsr128(ldsoff(&Bs[sl][wc64 + (j + 2) * 16 + m16][kp1]));
        }
        asm volatile("s_waitcnt lgkmcnt(0)");
        __builtin_amdgcn_sched_barrier(0);
        __builtin_amdgcn_s_setprio(1);
        #pragma unroll
        for (int i = 0; i < 4; ++i)
            #pragma unroll
            for (int j = 0; j < 2; ++j) {
                acc[i][j] = __builtin_amdgcn_mfma_f32_16x16x32_bf16(af[i][0], blo[j][0], acc[i][j], 0, 0, 0);
                acc[i][j] = __builtin_amdgcn_mfma_f32_16x16x32_bf16(af[i][1], blo[j][1], acc[i][j], 0, 0, 0);
                acc[i][j + 2] = __builtin_amdgcn_mfma_f32_16x16x32_bf16(af[i][0], bhi[j][0], acc[i][j + 2], 0, 0, 0);
                acc[i][j + 2] = __builtin_amdgcn_mfma_f32_16x16x32_bf16(af[i][1], bhi[j][1], acc[i][j + 2], 0, 0, 0);
            }
        __builtin_amdgcn_s_setprio(0);
        __builtin_amdgcn_s_barrier();   // F1

        // ===== phase B =====
        if (t + 2 < NT) { stageB(0, t + 2); stageB(1, t + 2); }
        #pragma unroll
        for (int i = 0; i < 4; ++i) {
            af[i][0] = dsr128(ldsoff(&As[sl][wr128 + 64 + i * 16 + m16][kp0]));
            af[i][1] = dsr128(ldsoff(&As[sl][wr128 + 64 + i * 16 + m16][kp1]));
        }
        asm volatile("s_waitcnt lgkmcnt(0)");
        __builtin_amdgcn_sched_barrier(0);
        __builtin_amdgcn_s_setprio(1);
        #pragma unroll
        for (int i = 0; i < 4; ++i)
            #pragma unroll
            for (int j = 0; j < 2; ++j) {
                acc[4 + i][j] = __builtin_amdgcn_mfma_f32_16x16x32_bf16(af[i][0], blo[j][0], acc[4 + i][j], 0, 0, 0);
                acc[4 + i][j] = __builtin_amdgcn_mfma_f32_16x16x32_bf16(af[i][1], blo[j][1], acc[4 + i][j], 0, 0, 0);
                acc[4 + i][j + 2] = __builtin_amdgcn_mfma_f32_16x16x32_bf16(af[i][0], bhi[j][0], acc[4 + i][j + 2], 0, 0, 0);
                acc[4 + i][j + 2] = __builtin_amdgcn_mfma_f32_16x16x32_bf16(af[i][1], bhi[j][1], acc[4 + i][j + 2], 0, 0, 0);
            }
        __builtin_amdgcn_s_setprio(0);
        if (t + 2 < NT) {
            asm volatile("s_waitcnt vmcnt(4)");
        } else {
            asm volatile("s_waitcnt vmcnt(0)");
        }
        __builtin_amdgcn_s_barrier();   // F2
    }

    // epilogue: bias (+gelu), C stride = DM
    #pragma unroll
    for (int i = 0; i < 8; ++i) {
        int row0 = bm + wr128 + i * 16 + quad * 4;
        #pragma unroll
        for (int j = 0; j < 4; ++j) {
            int col = bn + wc64 + j * 16 + m16;
            float bv = bias[col];
            #pragma unroll
            for (int r = 0; r < 4; ++r) {
                float v = acc[i][j][r] + bv;
                if (MODE == 2) {
                    float tt = tanhf(0.7978845608028654f * (v + 0.044715f * v * v * v));
                    ((bf16*)Cv)[(size_t)(row0 + r) * DM + col] = __float2bfloat16(0.5f * v * (1.f + tt));
                } else {
                    ((float*)Cv)[(size_t)(row0 + r) * DM + col] = v;
                }
            }
        }
    }
}

// ---------------------------------------------------------------------------
// Wave-per-chunk streaming chunk stage (R9, verified: total 215.6->206.1).
// ---------------------------------------------------------------------------
__global__ __launch_bounds__(256) void chunk_sums(const bf16* __restrict__ vb,
                                                  const float* __restrict__ kappa,
                                                  float* __restrict__ numbuf,
                                                  float* __restrict__ denbuf) {
    const int h = blockIdx.x;
    const int c = blockIdx.y * 4 + (threadIdx.x >> 6);
    const int v = threadIdx.x & 63;
    const size_t bidx = (size_t)h * NC + c;

    float kreg = kappa[(size_t)h * SEQ + c * 64 + v];   // lane v holds k[v]
    float num = 0.f;
    const short* vrow = (const short*)vb + (size_t)(c * 64) * DM + h * 64 + v;
    #pragma unroll 8
    for (int t = 0; t < 64; ++t) {
        float kt = __shfl(kreg, t);
        num += kt * bf2f(vrow[0]);
        vrow += DM;
    }
    numbuf[bidx * 64 + v] = num;
    float d = kreg;
    #pragma unroll
    for (int off = 32; off > 0; off >>= 1) d += __shfl_xor(d, off);
    if (v == 0) denbuf[bidx] = d;
}

__global__ __launch_bounds__(256) void chunk_scan(const bf16* __restrict__ vb,
                                                  const float* __restrict__ kappa,
                                                  const float* __restrict__ numbuf,
                                                  const float* __restrict__ denbuf,
                                                  bf16* __restrict__ out) {
    const int h = blockIdx.x;
    const int c = blockIdx.y * 4 + (threadIdx.x >> 6);
    const int v = threadIdx.x & 63;
    const size_t bidx = (size_t)h * NC + c;

    float kreg = kappa[(size_t)h * SEQ + c * 64 + v];
    float num = numbuf[bidx * 64 + v];    // exclusive prefix (coalesced)
    float den = denbuf[bidx];             // broadcast
    const short* vrow = (const short*)vb + (size_t)(c * 64) * DM + h * 64 + v;
    short* orow = (short*)out + (size_t)(c * 64) * DM + h * 64 + v;
    #pragma unroll 8
    for (int t = 0; t < 64; ++t) {
        float kt = __shfl(kreg, t);
        num += kt * bf2f(vrow[0]);
        den += kt;
        bf16 ob = __float2bfloat16(num / den);
        orow[0] = *(const short*)&ob;
        vrow += DM;
        orow += DM;
    }
}

// ---------------------------------------------------------------------------
// Exclusive prefix over chunks (unchanged).
// ---------------------------------------------------------------------------
__global__ __launch_bounds__(256) void prefix_state(float* __restrict__ numbuf,
                                                    float* __restrict__ denbuf) {
    const int h = blockIdx.x;
    const int wave = threadIdx.x >> 6;
    const int d = threadIdx.x & 63;
    __shared__ float tot[4][64];
    __shared__ float dtot[4];

    float val[32], dval[32];
    const int c0 = wave * 32;
    #pragma unroll
    for (int i = 0; i < 32; ++i) {
        size_t idx = (size_t)h * NC + c0 + i;
        val[i]  = numbuf[idx * 64 + d];
        dval[i] = denbuf[idx];
    }
    float run = 0.f, drun = 0.f;
    #pragma unroll
    for (int i = 0; i < 32; ++i) {
        float t = val[i];  val[i]  = run;  run  += t;
        float dt = dval[i]; dval[i] = drun; drun += dt;
    }
    tot[wave][d] = run;
    if (d == 0) dtot[wave] = drun;
    __syncthreads();
    float off = 0.f, doff = 0.f;
    for (int w = 0; w < wave; ++w) { off += tot[w][d]; doff += dtot[w]; }
    #pragma unroll
    for (int i = 0; i < 32; ++i) {
        size_t idx = (size_t)h * NC + c0 + i;
        numbuf[idx * 64 + d] = val[i] + off;
        if (d == 0) denbuf[idx] = dval[i] + doff;
    }
}

// ---------------------------------------------------------------------------
extern "C" void kernel_launch(void* const* d_in, const int* in_sizes, int n_in,
                              void* d_out, int out_size, void* d_ws, size_t ws_size,
                              hipStream_t stream) {
    const float* xs = (const float*)d_in[0];
    // d_in[1] = wq — provably unused: 'hkv,hq->hv' / 'hk,hq->h' sum k and q
    // independently, so the Sum(qa) factor cancels in sq/zq.
    const float* wk = (const float*)d_in[2];
    const float* wv = (const float*)d_in[3];
    const float* w1 = (const float*)d_in[4];
    const float* b1 = (const float*)d_in[5];
    const float* w2 = (const float*)d_in[6];
    const float* b2 = (const float*)d_in[7];
    float* y = (float*)d_out;

    char* base = (char*)d_ws;
    size_t off = 0;
    auto alloc = [&](size_t b) -> char* {
        char* p = base + off;
        off += (b + 255) & ~(size_t)255;
        return p;
    };

    const size_t NMAT = (size_t)SEQ * DM;      // 8.39M
    const size_t NW   = (size_t)DM * DM;       // 1.05M
    bf16*  xsb    = (bf16*)alloc(NMAT * 2);
    bf16*  wall   = (bf16*)alloc(4 * NW * 2);  // wk|wv|w1|w2, contiguous
    bf16*  w1b    = wall + 2 * NW;
    bf16*  w2b    = wall + 3 * NW;
    bf16*  vb     = (bf16*)alloc(NMAT * 2);    // V bf16
    float* kappa  = (float*)alloc((size_t)NH * SEQ * 4);
    float* numbuf = (float*)alloc((size_t)NH * NC * 64 * 4);
    float* denbuf = (float*)alloc((size_t)NH * NC * 4);
    bf16*  outb   = (bf16*)alloc(NMAT * 2);
    bf16*  hb     = (bf16*)alloc(NMAT * 2);

    // 1. all conversions in one launch (wq skipped)
    convert_all<<<8192 + 4 * 1024, 256, 0, stream>>>(xs, wk, wv, w1, w2,
                                                     xsb, wall);

    // 2. fused K|V projection: 256 blocks = full chip (R9 kernel, untouched)
    gemm256<<<dim3(2048 / 256, SEQ / 256), 512, 0, stream>>>(
        xsb, wall, vb, kappa, 2048);

    // 3. per-chunk sums, exclusive prefix, per-token scan (wave-per-chunk)
    chunk_sums<<<dim3(NH, NC / 4), 256, 0, stream>>>(vb, kappa, numbuf, denbuf);
    prefix_state<<<NH, 256, 0, stream>>>(numbuf, denbuf);
    chunk_scan<<<dim3(NH, NC / 4), 256, 0, stream>>>(vb, kappa, numbuf, denbuf,
                                                     outb);

    // 4. MLP via the 256^2-structure pair: grid (4,32) = 128 blocks.
    //    R10 measured this structure at 49.0us/dispatch vs gemm_mlp's 64.9.
    gemm_mlp256<2><<<dim3(DM / 256, SEQ / 256), 512, 0, stream>>>(
        outb, w1b, hb, b1);
    gemm_mlp256<3><<<dim3(DM / 256, SEQ / 256), 512, 0, stream>>>(
        hb, w2b, y, b2);
}

// Round 12
// 205.614 us; speedup vs baseline: 1.1370x; 1.1370x over previous
//
#include <hip/hip_runtime.h>
#include <hip/hip_bf16.h>

using bf16 = __hip_bfloat16;
typedef __attribute__((ext_vector_type(8))) short shortx8;  // 8 bf16 = 4 VGPRs (MFMA A/B frag)
typedef __attribute__((ext_vector_type(4))) float f32x4;    // MFMA C/D frag

#define SEQ 8192
#define DM 1024
#define NH 16
#define CHUNK 64
#define NC (SEQ / CHUNK)   // 128
#define NT (DM / 64)       // 16 K-tiles of BK=64

// async global->LDS, 16B per lane; LDS dest is wave-uniform base + lane*16
__device__ __forceinline__ void load_lds16(const bf16* g, bf16* l) {
    __builtin_amdgcn_global_load_lds(
        (const __attribute__((address_space(1))) void*)g,
        (__attribute__((address_space(3))) void*)l, 16, 0, 0);
}

// LDS byte offset (AS(3) pointers are 32-bit on AMDGPU)
__device__ __forceinline__ unsigned ldsoff(const bf16* p) {
    return (unsigned)(unsigned long long)(__attribute__((address_space(3))) const void*)p;
}

// inline-asm ds_read_b128: INVISIBLE to SIInsertWaitcnts, so the compiler
// cannot insert conservative vmcnt(0) drains against outstanding
// global_load_lds (R4-verified: 113us/5.6% MfmaUtil -> 50us/12.4%).
// Consumers fenced with s_waitcnt lgkmcnt(0) + sched_barrier(0) (rule #18).
__device__ __forceinline__ shortx8 dsr128(unsigned a) {
    shortx8 r;
    asm volatile("ds_read_b128 %0, %1" : "=v"(r) : "v"(a));
    return r;
}

__device__ __forceinline__ float bf2f(short s) {
    union { unsigned u; float f; } x;
    x.u = ((unsigned)(unsigned short)s) << 16;
    return x.f;
}

// ---------------------------------------------------------------------------
// One-shot fp32 -> bf16 conversion for xs + 4 weight matrices (unchanged).
// ---------------------------------------------------------------------------
__global__ __launch_bounds__(256) void convert_all(const float* __restrict__ xs,
                                                   const float* __restrict__ wk,
                                                   const float* __restrict__ wv,
                                                   const float* __restrict__ w1,
                                                   const float* __restrict__ w2,
                                                   bf16* __restrict__ xsb,
                                                   bf16* __restrict__ wall) {
    const int b = blockIdx.x;
    const float* in;
    bf16* out;
    int blk;
    if (b < 8192) {
        in = xs; out = xsb; blk = b;
    } else {
        const int seg = (b - 8192) >> 10;      // 0..3, uniform
        blk = (b - 8192) & 1023;
        out = wall + (size_t)seg * DM * DM;
        if (seg == 0)      in = wk;
        else if (seg == 1) in = wv;
        else if (seg == 2) in = w1;
        else               in = w2;
    }
    size_t i = ((size_t)blk * 256 + threadIdx.x) * 4;
    float4 f = *(const float4*)(in + i);
    out[i + 0] = __float2bfloat16(f.x);
    out[i + 1] = __float2bfloat16(f.y);
    out[i + 2] = __float2bfloat16(f.z);
    out[i + 3] = __float2bfloat16(f.w);
}

// ---------------------------------------------------------------------------
// KV projection GEMM (the 206.1us-config kernel, byte-identical revert).
// 256x256, N=2048 fused K|V, 256 blocks = full chip. R6 2-barrier schedule,
// asm ds_reads, counted vmcnt, O1 XCD swizzle.
// Fences per tile:
//   F1: BAR after phase A (all B reads of tile t complete before stageB
//       overwrites Bs[t&1]; per-wave lgkm(0) precedes its MFMA).
//   F2: counted gate vmcnt(4) (retires through A(t+1)) + BAR at tile end.
// ---------------------------------------------------------------------------
__global__ __launch_bounds__(512, 2) void gemm256(const bf16* __restrict__ A,
                                                  const bf16* __restrict__ B,
                                                  void* __restrict__ Cv,
                                                  float* __restrict__ kappa,
                                                  int N) {
    __shared__ __align__(16) bf16 As[2][256][64];   // 64KB
    __shared__ __align__(16) bf16 Bs[2][256][64];   // 64KB

    const int tid = threadIdx.x;
    const int nwg = gridDim.x * gridDim.y;
    const int bid = blockIdx.x + blockIdx.y * gridDim.x;
    const int cpx = nwg >> 3;                       // nwg % 8 == 0
    const int swz = (bid & 7) * cpx + (bid >> 3);   // bijective XCD chunking
    const int ry  = swz % gridDim.y;                // O1 orientation
    const int rx  = swz / gridDim.y;
    const int bm  = ry * 256;
    const int bn  = rx * 256;

    const int wave = tid >> 6;
    const int lane = tid & 63;
    const int wr   = wave >> 2;        // 0..1
    const int wc   = wave & 3;         // 0..3
    const int quad = lane >> 4;
    const int m16  = lane & 15;
    const int r7   = m16 & 7;
    const int wr128 = wr * 128;
    const int wc64  = wc * 64;
    const int kp0 = ((quad ^ r7) * 8);
    const int kp1 = (((4 + quad) ^ r7) * 8);

    auto stageA = [&](int half, int kt) {
        #pragma unroll
        for (int it = 0; it < 2; ++it) {
            int s = it * 512 + tid;          // 0..1023: (row = s>>3, pos = s&7)
            int row = s >> 3, pos = s & 7;
            int g = pos ^ (row & 7);
            load_lds16(A + (size_t)(bm + half * 128 + row) * DM + kt * 64 + g * 8,
                       &As[kt & 1][half * 128 + row][pos * 8]);
        }
    };
    auto stageB = [&](int half, int kt) {
        #pragma unroll
        for (int it = 0; it < 2; ++it) {
            int s = it * 512 + tid;
            int row = s >> 3, pos = s & 7;
            int g = pos ^ (row & 7);
            load_lds16(B + (size_t)(bn + half * 128 + row) * DM + kt * 64 + g * 8,
                       &Bs[kt & 1][half * 128 + row][pos * 8]);
        }
    };

    f32x4 acc[8][4];
    #pragma unroll
    for (int i = 0; i < 8; ++i)
        #pragma unroll
        for (int j = 0; j < 4; ++j)
            #pragma unroll
            for (int r = 0; r < 4; ++r) acc[i][j][r] = 0.f;

    // prologue: tile0 fully + B(1); tile0 landed via vmcnt(4)
    stageA(0, 0); stageA(1, 0); stageB(0, 0); stageB(1, 0);
    stageB(0, 1); stageB(1, 1);
    asm volatile("s_waitcnt vmcnt(4)");
    __builtin_amdgcn_s_barrier();

    shortx8 af[4][2], blo[2][2], bhi[2][2];

    #pragma unroll 1
    for (int t = 0; t < NT; ++t) {
        const int sl = t & 1;
        // ===== phase A: stage A(t+1), read A-lo + all B, MFMA q0+q1 =====
        if (t + 1 < NT) { stageA(0, t + 1); stageA(1, t + 1); }
        #pragma unroll
        for (int i = 0; i < 4; ++i) {
            af[i][0] = dsr128(ldsoff(&As[sl][wr128 + i * 16 + m16][kp0]));
            af[i][1] = dsr128(ldsoff(&As[sl][wr128 + i * 16 + m16][kp1]));
        }
        #pragma unroll
        for (int j = 0; j < 2; ++j) {
            blo[j][0] = dsr128(ldsoff(&Bs[sl][wc64 + j * 16 + m16][kp0]));
            blo[j][1] = dsr128(ldsoff(&Bs[sl][wc64 + j * 16 + m16][kp1]));
            bhi[j][0] = dsr128(ldsoff(&Bs[sl][wc64 + (j + 2) * 16 + m16][kp0]));
            bhi[j][1] = dsr128(ldsoff(&Bs[sl][wc64 + (j + 2) * 16 + m16][kp1]));
        }
        asm volatile("s_waitcnt lgkmcnt(0)");
        __builtin_amdgcn_sched_barrier(0);
        __builtin_amdgcn_s_setprio(1);
        #pragma unroll
        for (int i = 0; i < 4; ++i)
            #pragma unroll
            for (int j = 0; j < 2; ++j) {
                acc[i][j] = __builtin_amdgcn_mfma_f32_16x16x32_bf16(af[i][0], blo[j][0], acc[i][j], 0, 0, 0);
                acc[i][j] = __builtin_amdgcn_mfma_f32_16x16x32_bf16(af[i][1], blo[j][1], acc[i][j], 0, 0, 0);
                acc[i][j + 2] = __builtin_amdgcn_mfma_f32_16x16x32_bf16(af[i][0], bhi[j][0], acc[i][j + 2], 0, 0, 0);
                acc[i][j + 2] = __builtin_amdgcn_mfma_f32_16x16x32_bf16(af[i][1], bhi[j][1], acc[i][j + 2], 0, 0, 0);
            }
        __builtin_amdgcn_s_setprio(0);
        __builtin_amdgcn_s_barrier();   // F1: all B reads of tile t complete

        // ===== phase B: stage B(t+2), read A-hi, MFMA q2+q3, gate =====
        if (t + 2 < NT) { stageB(0, t + 2); stageB(1, t + 2); }
        #pragma unroll
        for (int i = 0; i < 4; ++i) {
            af[i][0] = dsr128(ldsoff(&As[sl][wr128 + 64 + i * 16 + m16][kp0]));
            af[i][1] = dsr128(ldsoff(&As[sl][wr128 + 64 + i * 16 + m16][kp1]));
        }
        asm volatile("s_waitcnt lgkmcnt(0)");
        __builtin_amdgcn_sched_barrier(0);
        __builtin_amdgcn_s_setprio(1);
        #pragma unroll
        for (int i = 0; i < 4; ++i)
            #pragma unroll
            for (int j = 0; j < 2; ++j) {
                acc[4 + i][j] = __builtin_amdgcn_mfma_f32_16x16x32_bf16(af[i][0], blo[j][0], acc[4 + i][j], 0, 0, 0);
                acc[4 + i][j] = __builtin_amdgcn_mfma_f32_16x16x32_bf16(af[i][1], blo[j][1], acc[4 + i][j], 0, 0, 0);
                acc[4 + i][j + 2] = __builtin_amdgcn_mfma_f32_16x16x32_bf16(af[i][0], bhi[j][0], acc[4 + i][j + 2], 0, 0, 0);
                acc[4 + i][j + 2] = __builtin_amdgcn_mfma_f32_16x16x32_bf16(af[i][1], bhi[j][1], acc[4 + i][j + 2], 0, 0, 0);
            }
        __builtin_amdgcn_s_setprio(0);
        if (t + 2 < NT) {
            asm volatile("s_waitcnt vmcnt(4)");   // retire through A(t+1)
        } else {
            asm volatile("s_waitcnt vmcnt(0)");
        }
        __builtin_amdgcn_s_barrier();   // F2: tile t+1 landed for all waves
    }

    // epilogue: C/D frag layout col = lane&15, row = quad*4 + reg
    const int gcol0 = bn + wc64;
    if (gcol0 < DM) {
        // K side: kappa[h][t] = sum_d act(K[t][h*64+d]); wave = one head
        const int h = gcol0 >> 6;
        #pragma unroll
        for (int i = 0; i < 8; ++i) {
            #pragma unroll
            for (int r = 0; r < 4; ++r) {
                float s = 0.f;
                #pragma unroll
                for (int j = 0; j < 4; ++j) {
                    float v = acc[i][j][r];
                    s += v > 0.f ? v + 1.f : __expf(v);
                }
                s += __shfl_xor(s, 1);
                s += __shfl_xor(s, 2);
                s += __shfl_xor(s, 4);
                s += __shfl_xor(s, 8);
                if (m16 == 0)
                    kappa[(size_t)h * SEQ + bm + wr128 + i * 16 + quad * 4 + r] = s;
            }
        }
    } else {
        // V side: bf16 store into vb
        bf16* vb = (bf16*)Cv;
        #pragma unroll
        for (int i = 0; i < 8; ++i) {
            int row0 = bm + wr128 + i * 16 + quad * 4;
            #pragma unroll
            for (int j = 0; j < 4; ++j) {
                int col = gcol0 - DM + j * 16 + m16;
                #pragma unroll
                for (int r = 0; r < 4; ++r)
                    vb[(size_t)(row0 + r) * DM + col] = __float2bfloat16(acc[i][j][r]);
            }
        }
    }
}

// ---------------------------------------------------------------------------
// MLP GEMM: 128x256 tile, 256 blocks = full chip, 3-slot A, R6 2-barrier
// schedule (the 206.1us-config kernel, byte-identical revert).
// phase A: stageA(t+2) -> 16 reads (all A + all B frags) -> lgkm ->
//          16 MFMA (j=0,1) -> BAR   (F1: all B reads of tile t complete)
// phase B: stageB(0/1,t+2) -> 16 MFMA (j=2,3; frags in regs) ->
//          gate vmcnt(6) -> BAR     (F2: tile t+1 landed)
// MODE 2: +bias, tanh-gelu -> bf16.  MODE 3: +bias -> fp32.
// ---------------------------------------------------------------------------
template <int MODE>
__global__ __launch_bounds__(512, 2) void gemm_mlp(const bf16* __restrict__ A,
                                                   const bf16* __restrict__ B,
                                                   void* __restrict__ Cv,
                                                   const float* __restrict__ bias,
                                                   int N) {
    __shared__ __align__(16) bf16 As[3][128][64];   // 48KB (3-slot rotation)
    __shared__ __align__(16) bf16 Bs[2][256][64];   // 64KB

    const int tid = threadIdx.x;
    const int nwg = gridDim.x * gridDim.y;
    const int bid = blockIdx.x + blockIdx.y * gridDim.x;
    const int cpx = nwg >> 3;                       // 256/8 = 32
    const int swz = (bid & 7) * cpx + (bid >> 3);   // bijective XCD chunking
    const int ry  = swz % gridDim.y;                // O1 orientation
    const int rx  = swz / gridDim.y;
    const int bm  = ry * 128;
    const int bn  = rx * 256;

    const int wave = tid >> 6;
    const int lane = tid & 63;
    const int wr   = wave >> 2;        // 0..1
    const int wc   = wave & 3;         // 0..3
    const int quad = lane >> 4;
    const int m16  = lane & 15;
    const int r7   = m16 & 7;
    const int wr64 = wr * 64;
    const int wc64 = wc * 64;
    const int kp0 = ((quad ^ r7) * 8);
    const int kp1 = (((4 + quad) ^ r7) * 8);

    auto stageA = [&](int slot, int kt) {
        #pragma unroll
        for (int it = 0; it < 2; ++it) {
            int s = it * 512 + tid;          // 1024 slots: 128 rows x 8 pos
            int row = s >> 3, pos = s & 7;
            int g = pos ^ (row & 7);
            load_lds16(A + (size_t)(bm + row) * DM + kt * 64 + g * 8,
                       &As[slot][row][pos * 8]);
        }
    };
    auto stageB = [&](int half, int kt) {
        #pragma unroll
        for (int it = 0; it < 2; ++it) {
            int s = it * 512 + tid;
            int row = s >> 3, pos = s & 7;
            int g = pos ^ (row & 7);
            load_lds16(B + (size_t)(bn + half * 128 + row) * DM + kt * 64 + g * 8,
                       &Bs[kt & 1][half * 128 + row][pos * 8]);
        }
    };

    f32x4 acc[4][4];
    #pragma unroll
    for (int i = 0; i < 4; ++i)
        #pragma unroll
        for (int j = 0; j < 4; ++j)
            #pragma unroll
            for (int r = 0; r < 4; ++r) acc[i][j][r] = 0.f;

    // prologue: tiles 0,1 staged; vmcnt(6) -> tile 0 landed, tile 1 in flight
    stageA(0, 0); stageB(0, 0); stageB(1, 0);
    stageA(1, 1); stageB(0, 1); stageB(1, 1);
    asm volatile("s_waitcnt vmcnt(6)");
    __builtin_amdgcn_s_barrier();

    shortx8 af[4][2], bfr[4][2];

    int sl3 = 0;   // A read slot  = t % 3
    int st3 = 2;   // A stage slot = (t+2) % 3

    #pragma unroll 1
    for (int t = 0; t < NT; ++t) {
        const int slB = t & 1;
        // ===== phase A: stage A(t+2), all 16 reads, MFMA j=0,1 =====
        if (t + 2 < NT) stageA(st3, t + 2);
        #pragma unroll
        for (int i = 0; i < 4; ++i) {
            af[i][0] = dsr128(ldsoff(&As[sl3][wr64 + i * 16 + m16][kp0]));
            af[i][1] = dsr128(ldsoff(&As[sl3][wr64 + i * 16 + m16][kp1]));
        }
        #pragma unroll
        for (int j = 0; j < 4; ++j) {
            bfr[j][0] = dsr128(ldsoff(&Bs[slB][wc64 + j * 16 + m16][kp0]));
            bfr[j][1] = dsr128(ldsoff(&Bs[slB][wc64 + j * 16 + m16][kp1]));
        }
        asm volatile("s_waitcnt lgkmcnt(0)");
        __builtin_amdgcn_sched_barrier(0);
        __builtin_amdgcn_s_setprio(1);
        #pragma unroll
        for (int i = 0; i < 4; ++i)
            #pragma unroll
            for (int j = 0; j < 2; ++j) {
                acc[i][j] = __builtin_amdgcn_mfma_f32_16x16x32_bf16(af[i][0], bfr[j][0], acc[i][j], 0, 0, 0);
                acc[i][j] = __builtin_amdgcn_mfma_f32_16x16x32_bf16(af[i][1], bfr[j][1], acc[i][j], 0, 0, 0);
            }
        __builtin_amdgcn_s_setprio(0);
        __builtin_amdgcn_s_barrier();   // F1: all B reads of tile t complete

        // ===== phase B: stage B(t+2), MFMA j=2,3 (reg-only), gate =====
        if (t + 2 < NT) { stageB(0, t + 2); stageB(1, t + 2); }
        __builtin_amdgcn_s_setprio(1);
        #pragma unroll
        for (int i = 0; i < 4; ++i)
            #pragma unroll
            for (int j = 0; j < 2; ++j) {
                acc[i][j + 2] = __builtin_amdgcn_mfma_f32_16x16x32_bf16(af[i][0], bfr[j + 2][0], acc[i][j + 2], 0, 0, 0);
                acc[i][j + 2] = __builtin_amdgcn_mfma_f32_16x16x32_bf16(af[i][1], bfr[j + 2][1], acc[i][j + 2], 0, 0, 0);
            }
        __builtin_amdgcn_s_setprio(0);
        if (t + 2 < NT) {
            asm volatile("s_waitcnt vmcnt(6)");   // retire through B(t+1)
        } else {
            asm volatile("s_waitcnt vmcnt(0)");
        }
        __builtin_amdgcn_s_barrier();   // F2: tile t+1 landed
        sl3 = (sl3 == 2) ? 0 : sl3 + 1;
        st3 = (st3 == 2) ? 0 : st3 + 1;
    }

    // epilogue
    #pragma unroll
    for (int i = 0; i < 4; ++i) {
        int row0 = bm + wr64 + i * 16 + quad * 4;
        #pragma unroll
        for (int j = 0; j < 4; ++j) {
            int col = bn + wc64 + j * 16 + m16;
            float bv = bias[col];
            #pragma unroll
            for (int r = 0; r < 4; ++r) {
                float v = acc[i][j][r] + bv;
                if (MODE == 2) {
                    float tt = tanhf(0.7978845608028654f * (v + 0.044715f * v * v * v));
                    ((bf16*)Cv)[(size_t)(row0 + r) * N + col] = __float2bfloat16(0.5f * v * (1.f + tt));
                } else {
                    ((float*)Cv)[(size_t)(row0 + r) * N + col] = v;
                }
            }
        }
    }
}

// ---------------------------------------------------------------------------
// Wave-per-chunk streaming chunk stage (verified: total 215.6->206.1).
// Lane v owns column v of one chunk; 64-step serial scan with coalesced
// 128B global V rows (L3-resident), zero LDS. kappa broadcast via __shfl.
// ---------------------------------------------------------------------------
__global__ __launch_bounds__(256) void chunk_sums(const bf16* __restrict__ vb,
                                                  const float* __restrict__ kappa,
                                                  float* __restrict__ numbuf,
                                                  float* __restrict__ denbuf) {
    const int h = blockIdx.x;
    const int c = blockIdx.y * 4 + (threadIdx.x >> 6);
    const int v = threadIdx.x & 63;
    const size_t bidx = (size_t)h * NC + c;

    float kreg = kappa[(size_t)h * SEQ + c * 64 + v];   // lane v holds k[v]
    float num = 0.f;
    const short* vrow = (const short*)vb + (size_t)(c * 64) * DM + h * 64 + v;
    #pragma unroll 8
    for (int t = 0; t < 64; ++t) {
        float kt = __shfl(kreg, t);
        num += kt * bf2f(vrow[0]);
        vrow += DM;
    }
    numbuf[bidx * 64 + v] = num;
    float d = kreg;
    #pragma unroll
    for (int off = 32; off > 0; off >>= 1) d += __shfl_xor(d, off);
    if (v == 0) denbuf[bidx] = d;
}

__global__ __launch_bounds__(256) void chunk_scan(const bf16* __restrict__ vb,
                                                  const float* __restrict__ kappa,
                                                  const float* __restrict__ numbuf,
                                                  const float* __restrict__ denbuf,
                                                  bf16* __restrict__ out) {
    const int h = blockIdx.x;
    const int c = blockIdx.y * 4 + (threadIdx.x >> 6);
    const int v = threadIdx.x & 63;
    const size_t bidx = (size_t)h * NC + c;

    float kreg = kappa[(size_t)h * SEQ + c * 64 + v];
    float num = numbuf[bidx * 64 + v];    // exclusive prefix (coalesced)
    float den = denbuf[bidx];             // broadcast
    const short* vrow = (const short*)vb + (size_t)(c * 64) * DM + h * 64 + v;
    short* orow = (short*)out + (size_t)(c * 64) * DM + h * 64 + v;
    #pragma unroll 8
    for (int t = 0; t < 64; ++t) {
        float kt = __shfl(kreg, t);
        num += kt * bf2f(vrow[0]);
        den += kt;
        bf16 ob = __float2bfloat16(num / den);
        orow[0] = *(const short*)&ob;
        vrow += DM;
        orow += DM;
    }
}

// ---------------------------------------------------------------------------
// Exclusive prefix over chunks (unchanged).
// ---------------------------------------------------------------------------
__global__ __launch_bounds__(256) void prefix_state(float* __restrict__ numbuf,
                                                    float* __restrict__ denbuf) {
    const int h = blockIdx.x;
    const int wave = threadIdx.x >> 6;
    const int d = threadIdx.x & 63;
    __shared__ float tot[4][64];
    __shared__ float dtot[4];

    float val[32], dval[32];
    const int c0 = wave * 32;
    #pragma unroll
    for (int i = 0; i < 32; ++i) {
        size_t idx = (size_t)h * NC + c0 + i;
        val[i]  = numbuf[idx * 64 + d];
        dval[i] = denbuf[idx];
    }
    float run = 0.f, drun = 0.f;
    #pragma unroll
    for (int i = 0; i < 32; ++i) {
        float t = val[i];  val[i]  = run;  run  += t;
        float dt = dval[i]; dval[i] = drun; drun += dt;
    }
    tot[wave][d] = run;
    if (d == 0) dtot[wave] = drun;
    __syncthreads();
    float off = 0.f, doff = 0.f;
    for (int w = 0; w < wave; ++w) { off += tot[w][d]; doff += dtot[w]; }
    #pragma unroll
    for (int i = 0; i < 32; ++i) {
        size_t idx = (size_t)h * NC + c0 + i;
        numbuf[idx * 64 + d] = val[i] + off;
        if (d == 0) denbuf[idx] = dval[i] + doff;
    }
}

// ---------------------------------------------------------------------------
extern "C" void kernel_launch(void* const* d_in, const int* in_sizes, int n_in,
                              void* d_out, int out_size, void* d_ws, size_t ws_size,
                              hipStream_t stream) {
    const float* xs = (const float*)d_in[0];
    // d_in[1] = wq — provably unused: 'hkv,hq->hv' / 'hk,hq->h' sum k and q
    // independently, so the Sum(qa) factor cancels in sq/zq.
    const float* wk = (const float*)d_in[2];
    const float* wv = (const float*)d_in[3];
    const float* w1 = (const float*)d_in[4];
    const float* b1 = (const float*)d_in[5];
    const float* w2 = (const float*)d_in[6];
    const float* b2 = (const float*)d_in[7];
    float* y = (float*)d_out;

    char* base = (char*)d_ws;
    size_t off = 0;
    auto alloc = [&](size_t b) -> char* {
        char* p = base + off;
        off += (b + 255) & ~(size_t)255;
        return p;
    };

    const size_t NMAT = (size_t)SEQ * DM;      // 8.39M
    const size_t NW   = (size_t)DM * DM;       // 1.05M
    bf16*  xsb    = (bf16*)alloc(NMAT * 2);
    bf16*  wall   = (bf16*)alloc(4 * NW * 2);  // wk|wv|w1|w2, contiguous
    bf16*  w1b    = wall + 2 * NW;
    bf16*  w2b    = wall + 3 * NW;
    bf16*  vb     = (bf16*)alloc(NMAT * 2);    // V bf16
    float* kappa  = (float*)alloc((size_t)NH * SEQ * 4);
    float* numbuf = (float*)alloc((size_t)NH * NC * 64 * 4);
    float* denbuf = (float*)alloc((size_t)NH * NC * 4);
    bf16*  outb   = (bf16*)alloc(NMAT * 2);
    bf16*  hb     = (bf16*)alloc(NMAT * 2);

    // 1. all conversions in one launch (wq skipped)
    convert_all<<<8192 + 4 * 1024, 256, 0, stream>>>(xs, wk, wv, w1, w2,
                                                     xsb, wall);

    // 2. fused K|V projection: 256 blocks = full chip
    gemm256<<<dim3(2048 / 256, SEQ / 256), 512, 0, stream>>>(
        xsb, wall, vb, kappa, 2048);

    // 3. per-chunk sums, exclusive prefix, per-token scan (wave-per-chunk)
    chunk_sums<<<dim3(NH, NC / 4), 256, 0, stream>>>(vb, kappa, numbuf, denbuf);
    prefix_state<<<NH, 256, 0, stream>>>(numbuf, denbuf);
    chunk_scan<<<dim3(NH, NC / 4), 256, 0, stream>>>(vb, kappa, numbuf, denbuf,
                                                     outb);

    // 4. MLP: 128x256 tile -> 4x64 = 256 blocks = full chip, 3-slot A
    gemm_mlp<2><<<dim3(DM / 256, SEQ / 128), 512, 0, stream>>>(
        outb, w1b, hb, b1, DM);
    gemm_mlp<3><<<dim3(DM / 256, SEQ / 128), 512, 0, stream>>>(
        hb, w2b, y, b2, DM);
}